// Round 6
// baseline (84.904 us; speedup 1.0000x reference)
//
#include <hip/hip_runtime.h>

#define NB 64        // bins
#define HW 65536     // pixels per channel (256*256)
#define NCH 24       // B*C = 8*3
#define SPLIT 32     // segments per channel-image
#define RAD 5        // truncation radius: dropped mass < 1.5e-7 relative
#define NSLOT 74     // slots: slot = bin + RAD, bin in [-5, 68]
#define NPAIR 37     // float2 pairs of slots

// w_j(x) = exp(-2048*(x - j/63)^2) = exp(-K*(f-j)^2), f = 63x, K = 2048/3969.
// For j = ni + r (ni = round(f), d = f - ni):
//   w = w0 * (e^{2Kd})^r * C_r,  w0 = e^{-K d^2},  C_r = e^{-K r^2}
// -> 3 transcendentals, 11 taps (|r| <= 5) at slots ni..ni+10.
// Accumulation: per-THREAD private LDS columns, PACKED AS float2 so the
// 12-slot parity-aligned window is 6 ds_read_b64 + 6 ds_write_b64 per pixel
// (vs 22 b32 ops). No atomics; DS completes in order per wave -> RMW safe.
__global__ __launch_bounds__(256) void chml_hist(const float* __restrict__ pred,
                                                 const float* __restrict__ targ,
                                                 float* __restrict__ part) {
  const int seg = blockIdx.x;   // 0..SPLIT-1
  const int ct  = blockIdx.y;   // 0..2*NCH-1
  const float* src = (ct < NCH) ? (pred + (size_t)ct * HW)
                                : (targ + (size_t)(ct - NCH) * HW);
  const int tid = threadIdx.x;

  __shared__ float2 h2[NPAIR][256];   // 75.8 KB; h2[s>>1][col] holds slots (2p, 2p+1)
  {
    float4* hz = (float4*)&h2[0][0];
#pragma unroll 2
    for (int i = tid; i < NPAIR * 256 / 2; i += 256)
      hz[i] = make_float4(0.f, 0.f, 0.f, 0.f);
  }
  __syncthreads();

  const float K  = 0.51599899f;      // 2048/3969
  const float C1 = 5.96905619e-01f;  // exp(-K*1)
  const float C2 = 1.26927917e-01f;  // exp(-K*4)
  const float C3 = 9.61165782e-03f;  // exp(-K*9)
  const float C4 = 2.59240329e-04f;  // exp(-K*16)
  const float C5 = 2.49029640e-06f;  // exp(-K*25)

  // segment = 2048 elems = 512 float4; 256 threads x 2 iterations, coalesced
  const float4* s4 = (const float4*)(src + (size_t)seg * (HW / SPLIT));
#pragma unroll
  for (int k = 0; k < (HW / SPLIT) / (4 * 256); ++k) {
    float4 p = s4[k * 256 + tid];
    float pe[4] = {p.x, p.y, p.z, p.w};
#pragma unroll
    for (int e4 = 0; e4 < 4; ++e4) {
      float f = pe[e4] * 63.0f;
      float n = rintf(f);
      float d = f - n;            // [-0.5, 0.5]
      int  ni = (int)n;           // 0..63
      float w0 = __expf(d * d * -K);
      float mp = __expf(d * (2.0f * K));   // e^{+2Kd}
      float mn = __expf(d * (-2.0f * K));  // e^{-2Kd}
      float mp2 = mp * mp, mp3 = mp2 * mp, mp4 = mp2 * mp2, mp5 = mp4 * mp;
      float mn2 = mn * mn, mn3 = mn2 * mn, mn4 = mn2 * mn2, mn5 = mn4 * mn;
      float A1 = w0 * C1, A2 = w0 * C2, A3 = w0 * C3, A4 = w0 * C4, A5 = w0 * C5;
      float wt[11];
      wt[0]  = A5 * mn5;  // r = -5, slot ni
      wt[1]  = A4 * mn4;
      wt[2]  = A3 * mn3;
      wt[3]  = A2 * mn2;
      wt[4]  = A1 * mn;
      wt[5]  = w0;        // r = 0
      wt[6]  = A1 * mp;
      wt[7]  = A2 * mp2;
      wt[8]  = A3 * mp3;
      wt[9]  = A4 * mp4;
      wt[10] = A5 * mp5;  // r = +5, slot ni+10
      // Parity-align to the float2 grid: window = slots (ni-e) .. (ni-e)+11,
      // e = ni&1. w12[j] covers slot (ni-e)+j; one end is a zero pad.
      const int e = ni & 1;
      float w12[12];
      w12[0] = e ? 0.0f : wt[0];
#pragma unroll
      for (int j = 1; j < 11; ++j) w12[j] = e ? wt[j - 1] : wt[j];
      w12[11] = e ? wt[10] : 0.0f;

      float2* col2 = &h2[(ni - e) >> 1][tid];   // pair q at col2[q*256]
      float2 t[6];
#pragma unroll
      for (int q = 0; q < 6; ++q) t[q] = col2[q * 256];
#pragma unroll
      for (int q = 0; q < 6; ++q) {
        t[q].x += w12[2 * q];
        t[q].y += w12[2 * q + 1];
        col2[q * 256] = t[q];
      }
    }
  }
  __syncthreads();

  // Fold 256 columns -> 1 for the 64 real bins (slots RAD..RAD+63).
  float* hf = (float*)&h2[0][0];   // hval(s,c) = hf[(s>>1)*512 + c*2 + (s&1)]
#pragma unroll
  for (int st = 128; st >= 1; st >>= 1) {
    for (int idx = tid; idx < NB * st; idx += 256) {
      int s = idx / st + RAD, c = idx % st;   // st literal pow2 -> shifts
      hf[(s >> 1) * 512 + c * 2 + (s & 1)] +=
          hf[(s >> 1) * 512 + (c + st) * 2 + (s & 1)];
    }
    __syncthreads();
  }
  if (tid < NB) {
    int s = tid + RAD;
    part[((size_t)ct * SPLIT + seg) * NB + tid] =
        hf[(s >> 1) * 512 + (s & 1)];
  }
}

// Finish: sum segment partials, normalize, cumsum, mean |cdf diff|.
// 1 block, 8 waves; lane = bin.
__global__ __launch_bounds__(512) void chml_finish(const float* __restrict__ part,
                                                   float* __restrict__ out) {
  const int tid  = threadIdx.x;
  const int lane = tid & 63;
  const int wave = tid >> 6;  // 0..7
  float lsum = 0.0f;
  for (int c = wave; c < NCH; c += 8) {
    float vp = 0.0f, vt = 0.0f;
#pragma unroll
    for (int s = 0; s < SPLIT; ++s) {
      vp += part[((size_t)c * SPLIT + s) * NB + lane];
      vt += part[((size_t)(c + NCH) * SPLIT + s) * NB + lane];
    }
    // inclusive prefix scan across 64 lanes (Hillis-Steele)
#pragma unroll
    for (int off = 1; off < 64; off <<= 1) {
      float up = __shfl_up(vp, off, 64);
      float ut = __shfl_up(vt, off, 64);
      if (lane >= off) { vp += up; vt += ut; }
    }
    float totp = __shfl(vp, 63, 64);
    float tott = __shfl(vt, 63, 64);
    lsum += fabsf(vp / (totp + 1e-7f) - vt / (tott + 1e-7f));
  }
#pragma unroll
  for (int off = 32; off >= 1; off >>= 1) lsum += __shfl_xor(lsum, off, 64);
  __shared__ float red[8];
  if (lane == 0) red[wave] = lsum;
  __syncthreads();
  if (tid == 0) {
    float t = (red[0] + red[1]) + (red[2] + red[3]) +
              (red[4] + red[5]) + (red[6] + red[7]);
    out[0] = t * (1.0f / (float)(NCH * NB));
  }
}

extern "C" void kernel_launch(void* const* d_in, const int* in_sizes, int n_in,
                              void* d_out, int out_size, void* d_ws, size_t ws_size,
                              hipStream_t stream) {
  const float* pred = (const float*)d_in[0];
  const float* targ = (const float*)d_in[1];
  float* part = (float*)d_ws;   // 2*NCH*SPLIT*NB floats = 384 KB

  dim3 grid(SPLIT, 2 * NCH);
  chml_hist<<<grid, 256, 0, stream>>>(pred, targ, part);
  chml_finish<<<1, 512, 0, stream>>>(part, (float*)d_out);
}